// Round 3
// baseline (373.344 us; speedup 1.0000x reference)
//
#include <hip/hip_runtime.h>
#include <hip/hip_bf16.h>
#include <cstdint>

// SNN: Poisson encode (noise < x) -> [T=32] { h = sp@W1^T; v+=h; spike=(v>1); v-=spike; logits += spike@W2^T }
// B=8192, T=32, D_IN=784 (pad K to 800 = 25x32), D_H=100 (pad N to 128), D_OUT=10.
//
//  K0 prep_w1 : W1 -> MFMA-B-fragment-layout bf16 hi/lo pairs in ws.
//  K1 snn_gemm: H[t,b,h] via mfma_f32_16x16x32_bf16. v3: reg-stage noise+x with
//               coalesced float4 loads, compare AT STAGE TIME (exact f32), write
//               packed bf16 SPIKES to LDS (8KB/tile, dbuf, ONE barrier/kt).
//               Next-tile loads issue before MFMAs (T14). XCD-swizzled blocks.
//  K2 snn_scan: IF scan over t, then logits = spikecount @ W2^T (W2 t-invariant).

typedef __attribute__((ext_vector_type(8))) short bf16x8;
typedef __attribute__((ext_vector_type(4))) float f32x4;

#define D_IN 784
#define NB 8192
#define KT 25   // K tiles of 32 (800 padded)
#define NTL 8   // N tiles of 16 (128 padded)
#define DH 100

// ---------------- K0: pack W1 into fragment-ready bf16 hi/lo ----------------
// Fragment f = (kt*8 + nt), stored as [f][hi(512 ushorts) | lo(512 ushorts)].
// B-slot(lane l, elem j): n = nt*16 + (l&15), i = kt*32 + (l>>4)*8 + j.
__global__ void prep_w1(const float* __restrict__ W1, unsigned short* __restrict__ wf) {
    int idx = blockIdx.x * 256 + threadIdx.x;           // 25*8*64 = 12800
    if (idx >= KT * NTL * 64) return;
    int l  = idx & 63;
    int nt = (idx >> 6) & 7;
    int kt = idx >> 9;
    int n  = nt * 16 + (l & 15);
    int i0 = kt * 32 + (l >> 4) * 8;
    size_t fbase = (size_t)(kt * 8 + nt) * 1024;
    #pragma unroll
    for (int j = 0; j < 8; ++j) {
        int i = i0 + j;
        float w = (n < DH && i < D_IN) ? W1[n * D_IN + i] : 0.f;
        uint32_t ub = __float_as_uint(w);
        uint32_t rh = ub + 0x7FFFu + ((ub >> 16) & 1u);
        unsigned short h = (unsigned short)(rh >> 16);
        float hf = __uint_as_float(((uint32_t)h) << 16);
        float resid = w - hf;
        uint32_t ul = __float_as_uint(resid);
        uint32_t rl = ul + 0x7FFFu + ((ul >> 16) & 1u);
        unsigned short lo = (unsigned short)(rl >> 16);
        wf[fbase + l * 8 + j]       = h;
        wf[fbase + 512 + l * 8 + j] = lo;
    }
}

// ---------------- K1: H = spikes @ W1^T for all (t,b) ----------------
// Block: 256 thr = 4 waves as 2(M)x2(N); tile 128 rows x 128 h; grid 2048 = 32t x 64 btiles.
// LDS: spike tile [128 rows][32 bf16] = 8KB, double-buffered.
// Granule = 8 bf16 (16B); 4 granules/row; swizzle g' = g ^ ((row>>1)&3)
//   -> each 16-lane read group covers all 32 banks (2-way = free).
__global__ __launch_bounds__(256) void snn_gemm(const float* __restrict__ x,
                                                const float* __restrict__ noise,
                                                const unsigned short* __restrict__ wf,
                                                float* __restrict__ H) {
    __shared__ __align__(16) unsigned short sS[2][4096];   // 2 x 8KB
    const int tid   = threadIdx.x;
    const int lane  = tid & 63;
    const int wave  = tid >> 6;
    const int Mhalf = wave >> 1;
    const int Nhalf = wave & 1;
    // XCD swizzle: xcd = L&7 owns btiles {8*xcd .. 8*xcd+7} for ALL t -> x slice 3.2MB/XCD L2-resident.
    const int L     = blockIdx.x;
    const int btile = (L & 7) * 8 + ((L >> 3) & 7);
    const int t     = L >> 6;
    const int b0    = btile * 128;
    const float* nb = noise + (size_t)t * ((size_t)NB * D_IN);

    // staging map: thread handles f32-granules gg = i*256+tid; row = gg>>3, gcol = gg&7
    int sRow[4], sGcol[4], wOff[4];
    #pragma unroll
    for (int i = 0; i < 4; ++i) {
        int gg = i * 256 + tid;
        sRow[i]  = gg >> 3;
        sGcol[i] = gg & 7;
        int g  = sGcol[i] >> 1;
        int gp = g ^ ((sRow[i] >> 1) & 3);
        wOff[i] = sRow[i] * 32 + gp * 8 + (sGcol[i] & 1) * 4;   // ushort idx
    }
    // fragment read offsets: row = Mhalf*64+mt*16+(lane&15), granule g = lane>>4
    int fOff[4];
    #pragma unroll
    for (int mt = 0; mt < 4; ++mt) {
        int row = Mhalf * 64 + mt * 16 + (lane & 15);
        int gp  = (lane >> 4) ^ ((row >> 1) & 3);
        fOff[mt] = row * 32 + gp * 8;
    }

    f32x4 acc[4][4];
    #pragma unroll
    for (int i = 0; i < 4; ++i)
        #pragma unroll
        for (int j = 0; j < 4; ++j) acc[i][j] = (f32x4){0.f, 0.f, 0.f, 0.f};

    // ---- prologue: stage kt=0 into buf0 ----
    {
        #pragma unroll
        for (int i = 0; i < 4; ++i) {
            const size_t ro = (size_t)(b0 + sRow[i]) * D_IN + sGcol[i] * 4;
            const float4 nv = *reinterpret_cast<const float4*>(nb + ro);
            const float4 xv = *reinterpret_cast<const float4*>(x + ro);
            uint32_t u0 = (nv.x < xv.x ? 0x3F80u : 0u) | (nv.y < xv.y ? 0x3F800000u : 0u);
            uint32_t u1 = (nv.z < xv.z ? 0x3F80u : 0u) | (nv.w < xv.w ? 0x3F800000u : 0u);
            *reinterpret_cast<uint2*>(&sS[0][wOff[i]]) = make_uint2(u0, u1);
        }
        __syncthreads();
    }

    #pragma unroll 1
    for (int kt = 0; kt < KT; ++kt) {
        const unsigned short* rb = &sS[kt & 1][0];
        unsigned short*       wb = &sS[(kt & 1) ^ 1][0];

        // issue next-tile global loads EARLY (latency hides under MFMAs)
        float4 nr[4], xr[4];
        if (kt < KT - 1) {
            #pragma unroll
            for (int i = 0; i < 4; ++i) {
                int c = (kt + 1) * 32 + sGcol[i] * 4;
                if (kt + 1 == KT - 1 && sGcol[i] >= 4) c = (KT - 1) * 32;  // clamp (W1 pad=0 covers)
                const size_t ro = (size_t)(b0 + sRow[i]) * D_IN + c;
                nr[i] = *reinterpret_cast<const float4*>(nb + ro);
                xr[i] = *reinterpret_cast<const float4*>(x + ro);
            }
        }

        // compute kt from rb
        bf16x8 afr[4];
        #pragma unroll
        for (int mt = 0; mt < 4; ++mt)
            afr[mt] = *reinterpret_cast<const bf16x8*>(rb + fOff[mt]);
        #pragma unroll
        for (int nt = 0; nt < 4; ++nt) {
            const size_t fo = (size_t)(kt * 8 + Nhalf * 4 + nt) * 1024 + lane * 8;
            const bf16x8 bhi = *reinterpret_cast<const bf16x8*>(wf + fo);
            const bf16x8 blo = *reinterpret_cast<const bf16x8*>(wf + fo + 512);
            #pragma unroll
            for (int mt = 0; mt < 4; ++mt) {
                acc[mt][nt] = __builtin_amdgcn_mfma_f32_16x16x32_bf16(afr[mt], bhi, acc[mt][nt], 0, 0, 0);
                acc[mt][nt] = __builtin_amdgcn_mfma_f32_16x16x32_bf16(afr[mt], blo, acc[mt][nt], 0, 0, 0);
            }
        }

        // pack + write spikes for kt+1 into the other buffer
        if (kt < KT - 1) {
            #pragma unroll
            for (int i = 0; i < 4; ++i) {
                uint32_t u0 = (nr[i].x < xr[i].x ? 0x3F80u : 0u) | (nr[i].y < xr[i].y ? 0x3F800000u : 0u);
                uint32_t u1 = (nr[i].z < xr[i].z ? 0x3F80u : 0u) | (nr[i].w < xr[i].w ? 0x3F800000u : 0u);
                *reinterpret_cast<uint2*>(&wb[wOff[i]]) = make_uint2(u0, u1);
            }
        }
        __syncthreads();
    }

    // C/D layout: col = lane&15, row = (lane>>4)*4 + reg.  H compact [.,100].
    const int colBase   = Nhalf * 64 + (lane & 15);
    const int rowInTile = (lane >> 4) * 4;
    #pragma unroll
    for (int mt = 0; mt < 4; ++mt) {
        const size_t rg = (size_t)t * NB + b0 + Mhalf * 64 + mt * 16 + rowInTile;
        #pragma unroll
        for (int nt = 0; nt < 4; ++nt) {
            const int col = colBase + nt * 16;
            if (col < DH) {
                #pragma unroll
                for (int r = 0; r < 4; ++r)
                    H[(rg + r) * DH + col] = acc[mt][nt][r];
            }
        }
    }
}

// ---------------- K2: IF scan over t + logits = cnt @ W2^T ----------------
__global__ __launch_bounds__(256) void snn_scan(const float* __restrict__ H,
                                                const float* __restrict__ W2,
                                                float* __restrict__ out) {
    __shared__ float cbuf[2][104];
    __shared__ float w2s[1000];
    const int tid = threadIdx.x;
    const int r = tid >> 7, h = tid & 127;
    const size_t b = (size_t)blockIdx.x * 2 + r;
    for (int i = tid; i < 1000; i += 256) w2s[i] = W2[i];

    float cnt = 0.f;
    if (h < DH) {
        float hv[32];
        #pragma unroll
        for (int t = 0; t < 32; ++t) hv[t] = H[((size_t)t * NB + b) * DH + h];
        float v = 0.f;
        #pragma unroll
        for (int t = 0; t < 32; ++t) {
            v += hv[t];
            float s = (v - 1.0f > 0.0f) ? 1.0f : 0.0f;  // exact reference semantics
            v -= s;
            cnt += s;
        }
    }
    if (h < DH) cbuf[r][h] = cnt;
    __syncthreads();
    if (tid < 20) {
        const int rr = tid / 10, o = tid % 10;
        float s = 0.f;
        for (int hh = 0; hh < DH; ++hh) s += cbuf[rr][hh] * w2s[o * DH + hh];
        out[((size_t)blockIdx.x * 2 + rr) * 10 + o] = s;
    }
}

extern "C" void kernel_launch(void* const* d_in, const int* in_sizes, int n_in,
                              void* d_out, int out_size, void* d_ws, size_t ws_size,
                              hipStream_t stream) {
    const float* x     = (const float*)d_in[0];   // [8192,784]
    const float* noise = (const float*)d_in[1];   // [32,8192,784]
    const float* W1    = (const float*)d_in[2];   // [100,784]
    const float* W2    = (const float*)d_in[3];   // [10,100]
    float* out = (float*)d_out;                   // [8192,10]

    unsigned short* wf = (unsigned short*)d_ws;                    // 409.6 KB W1 frags
    float* H = (float*)((char*)d_ws + (1u << 20));                 // 104.9 MB H buffer

    prep_w1<<<50, 256, 0, stream>>>(W1, wf);
    snn_gemm<<<2048, 256, 0, stream>>>(x, noise, wf, H);
    snn_scan<<<4096, 256, 0, stream>>>(H, W2, out);
}

// Round 4
// 370.015 us; speedup vs baseline: 1.0090x; 1.0090x over previous
//
#include <hip/hip_runtime.h>
#include <hip/hip_bf16.h>
#include <cstdint>

// SNN: Poisson encode (noise < x) -> [T=32] { h = sp@W1^T; v+=h; spike=(v>1); v-=spike; logits += spike@W2^T }
// B=8192, T=32, D_IN=784 (pad K to 800 = 25x32), D_H=100 (pad N to 128), D_OUT=10.
//
// v4: decouple the noise stream from the MFMA loop.
//  K0 prep_w1   : W1 -> MFMA-B-fragment bf16 hi/lo pairs in ws (exact f32 = hi+lo).
//  K1 spike_pack: stream noise+x once, __ballot-pack spike bits -> bits[t][kt][b] dword
//                 (bit p = spike(b, i=kt*32+p)). Pure BW kernel, x held in-register over t.
//  K2 bit_gemm  : H[t,b,h] via mfma_f32_16x16x32_bf16. NO LDS, NO barriers: A-fragment
//                 = bit-extract from one broadcast dword/row; B from wf (L2-resident).
//  K3 snn_scan  : IF scan over t, logits = spikecount @ W2^T (W2 t-invariant).

typedef __attribute__((ext_vector_type(8))) short bf16x8;
typedef __attribute__((ext_vector_type(4))) float f32x4;

#define D_IN 784
#define NB 8192
#define KT 25   // K tiles of 32 (800 padded)
#define NTL 8   // N tiles of 16 (128 padded)
#define DH 100

// ---------------- K0: pack W1 into fragment-ready bf16 hi/lo ----------------
// Fragment f = (kt*8 + nt), stored as [f][hi(512 ushorts) | lo(512 ushorts)].
// B-slot(lane l, elem j): n = nt*16 + (l&15), i = kt*32 + (l>>4)*8 + j.
__global__ void prep_w1(const float* __restrict__ W1, unsigned short* __restrict__ wf) {
    int idx = blockIdx.x * 256 + threadIdx.x;           // 25*8*64 = 12800
    if (idx >= KT * NTL * 64) return;
    int l  = idx & 63;
    int nt = (idx >> 6) & 7;
    int kt = idx >> 9;
    int n  = nt * 16 + (l & 15);
    int i0 = kt * 32 + (l >> 4) * 8;
    size_t fbase = (size_t)(kt * 8 + nt) * 1024;
    #pragma unroll
    for (int j = 0; j < 8; ++j) {
        int i = i0 + j;
        float w = (n < DH && i < D_IN) ? W1[n * D_IN + i] : 0.f;
        uint32_t ub = __float_as_uint(w);
        uint32_t rh = ub + 0x7FFFu + ((ub >> 16) & 1u);
        unsigned short h = (unsigned short)(rh >> 16);
        float hf = __uint_as_float(((uint32_t)h) << 16);
        float resid = w - hf;
        uint32_t ul = __float_as_uint(resid);
        uint32_t rl = ul + 0x7FFFu + ((ul >> 16) & 1u);
        unsigned short lo = (unsigned short)(rl >> 16);
        wf[fbase + l * 8 + j]       = h;
        wf[fbase + 512 + l * 8 + j] = lo;
    }
}

// ---------------- K1: spike bitpack ----------------
// Wave w covers b-pair {2*(w/25), +1} x kt = w%25. Lane: b = bp*2 + (lane>>5),
// i = kt*32 + (lane&31). x loaded once; all 32 t noise loads issued up front
// (32 in flight), then 32x { ballot -> 2-lane dword store }.
__global__ __launch_bounds__(256) void spike_pack(const float* __restrict__ x,
                                                  const float* __restrict__ noise,
                                                  uint32_t* __restrict__ bits) {
    const int tid  = threadIdx.x;
    const int lane = tid & 63;
    const int w    = blockIdx.x * 4 + (tid >> 6);       // 0 .. 102399
    const int kt   = w % 25;
    const int bp   = w / 25;
    const int b    = bp * 2 + (lane >> 5);
    const int i    = kt * 32 + (lane & 31);
    const int ic   = i < D_IN ? i : D_IN - 1;
    const bool valid = (i < D_IN);
    const size_t ro = (size_t)b * D_IN + ic;
    const float xv  = x[ro];
    float nv[32];
    #pragma unroll
    for (int t = 0; t < 32; ++t)
        nv[t] = noise[(size_t)t * ((size_t)NB * D_IN) + ro];
    #pragma unroll
    for (int t = 0; t < 32; ++t) {
        unsigned long long m = __ballot(valid && (nv[t] < xv));
        if ((lane & 31) == 0)
            bits[(size_t)(t * KT + kt) * NB + b] = (uint32_t)(m >> lane);
    }
}

// ---------------- K2: H = spikes @ W1^T, bits input, no LDS/barriers ----------------
// Block: 256 thr = 4 waves as 2(M)x2(N); tile 128 rows x 128 h; grid 2048 = 32t x 64 btiles.
// A-fragment: one dword bits[t][kt][row] per (mt); lane extracts bits (lane>>4)*8 + j.
__global__ __launch_bounds__(256) void bit_gemm(const uint32_t* __restrict__ bits,
                                                const unsigned short* __restrict__ wf,
                                                float* __restrict__ H) {
    const int tid   = threadIdx.x;
    const int lane  = tid & 63;
    const int wave  = tid >> 6;
    const int Mhalf = wave >> 1;
    const int Nhalf = wave & 1;
    const int bid   = blockIdx.x;
    const int btile = bid & 63;
    const int t     = bid >> 6;
    const int b0    = btile * 128;
    const int rowBase = b0 + Mhalf * 64 + (lane & 15);
    const int sh      = (lane >> 4) * 8;

    f32x4 acc[4][4];
    #pragma unroll
    for (int i = 0; i < 4; ++i)
        #pragma unroll
        for (int j = 0; j < 4; ++j) acc[i][j] = (f32x4){0.f, 0.f, 0.f, 0.f};

    #pragma unroll 2
    for (int kt = 0; kt < KT; ++kt) {
        const uint32_t* bptr = bits + (size_t)(t * KT + kt) * NB;
        uint32_t g[4];
        #pragma unroll
        for (int mt = 0; mt < 4; ++mt) g[mt] = bptr[rowBase + mt * 16];

        bf16x8 afr[4];
        #pragma unroll
        for (int mt = 0; mt < 4; ++mt) {
            union { uint32_t u[4]; bf16x8 v; } pk;
            #pragma unroll
            for (int d = 0; d < 4; ++d) {
                const uint32_t b2 = (g[mt] >> (sh + d * 2)) & 3u;
                pk.u[d] = ((b2 & 1u) ? 0x3F80u : 0u) | ((b2 & 2u) ? 0x3F800000u : 0u);
            }
            afr[mt] = pk.v;
        }
        #pragma unroll
        for (int nt = 0; nt < 4; ++nt) {
            const size_t fo = (size_t)(kt * 8 + Nhalf * 4 + nt) * 1024 + lane * 8;
            const bf16x8 bhi = *reinterpret_cast<const bf16x8*>(wf + fo);
            const bf16x8 blo = *reinterpret_cast<const bf16x8*>(wf + fo + 512);
            #pragma unroll
            for (int mt = 0; mt < 4; ++mt) {
                acc[mt][nt] = __builtin_amdgcn_mfma_f32_16x16x32_bf16(afr[mt], bhi, acc[mt][nt], 0, 0, 0);
                acc[mt][nt] = __builtin_amdgcn_mfma_f32_16x16x32_bf16(afr[mt], blo, acc[mt][nt], 0, 0, 0);
            }
        }
    }
    // C/D layout: col = lane&15, row = (lane>>4)*4 + reg.  H compact [.,100].
    const int colBase   = Nhalf * 64 + (lane & 15);
    const int rowInTile = (lane >> 4) * 4;
    #pragma unroll
    for (int mt = 0; mt < 4; ++mt) {
        const size_t rg = (size_t)t * NB + b0 + Mhalf * 64 + mt * 16 + rowInTile;
        #pragma unroll
        for (int nt = 0; nt < 4; ++nt) {
            const int col = colBase + nt * 16;
            if (col < DH) {
                #pragma unroll
                for (int r = 0; r < 4; ++r)
                    H[(rg + r) * DH + col] = acc[mt][nt][r];
            }
        }
    }
}

// ---------------- K3: IF scan over t + logits = cnt @ W2^T ----------------
__global__ __launch_bounds__(256) void snn_scan(const float* __restrict__ H,
                                                const float* __restrict__ W2,
                                                float* __restrict__ out) {
    __shared__ float cbuf[2][104];
    __shared__ float w2s[1000];
    const int tid = threadIdx.x;
    const int r = tid >> 7, h = tid & 127;
    const size_t b = (size_t)blockIdx.x * 2 + r;
    for (int i = tid; i < 1000; i += 256) w2s[i] = W2[i];

    float cnt = 0.f;
    if (h < DH) {
        float hv[32];
        #pragma unroll
        for (int t = 0; t < 32; ++t) hv[t] = H[((size_t)t * NB + b) * DH + h];
        float v = 0.f;
        #pragma unroll
        for (int t = 0; t < 32; ++t) {
            v += hv[t];
            float s = (v - 1.0f > 0.0f) ? 1.0f : 0.0f;  // exact reference semantics
            v -= s;
            cnt += s;
        }
    }
    if (h < DH) cbuf[r][h] = cnt;
    __syncthreads();
    if (tid < 20) {
        const int rr = tid / 10, o = tid % 10;
        float s = 0.f;
        for (int hh = 0; hh < DH; ++hh) s += cbuf[rr][hh] * w2s[o * DH + hh];
        out[((size_t)blockIdx.x * 2 + rr) * 10 + o] = s;
    }
}

extern "C" void kernel_launch(void* const* d_in, const int* in_sizes, int n_in,
                              void* d_out, int out_size, void* d_ws, size_t ws_size,
                              hipStream_t stream) {
    const float* x     = (const float*)d_in[0];   // [8192,784]
    const float* noise = (const float*)d_in[1];   // [32,8192,784]
    const float* W1    = (const float*)d_in[2];   // [100,784]
    const float* W2    = (const float*)d_in[3];   // [10,100]
    float* out = (float*)d_out;                   // [8192,10]

    unsigned short* wf = (unsigned short*)d_ws;                      // 400 KB W1 frags
    uint32_t* bits = (uint32_t*)((char*)d_ws + (1u << 20));          // 26.2 MB spike bits
    float* H = (float*)((char*)d_ws + (32u << 20));                  // 104.9 MB H buffer

    prep_w1<<<50, 256, 0, stream>>>(W1, wf);
    spike_pack<<<25600, 256, 0, stream>>>(x, noise, bits);
    bit_gemm<<<2048, 256, 0, stream>>>(bits, wf, H);
    snn_scan<<<4096, 256, 0, stream>>>(H, W2, out);
}